// Round 12
// baseline (163.520 us; speedup 1.0000x reference)
//
#include <hip/hip_runtime.h>

#define NCLASS 100
#define HID    768
#define BATCH  512
#define SG     8
#define NPAN   12
#define BH     (BATCH * HID)

// Work-balanced row-block boundaries for kA2 (all multiples of 4; suffix work
// sum_{h in [lo,hi)} (768-h) approx equal for each of the 12 blocks).
__constant__ int hb_tab[13] = {0, 32, 68, 104, 140, 180, 224, 272, 324, 384, 456, 548, 768};

// Deterministic per-class sample list (wave 0 of each block).
__device__ __forceinline__ void build_list(const int* __restrict__ y, int c,
                                           int* slist, int* scnt, int t) {
    if (t < 64) {
        int n = 0;
        for (int r = 0; r < BATCH / 64; ++r) {
            const int b = r * 64 + t;
            const bool hit = (y[b] == c);
            const unsigned long long mask = __ballot(hit);
            if (hit) slist[n + __popcll(mask & ((1ull << t) - 1ull))] = b;
            n += __popcll(mask);
        }
        if (t == 0) *scnt = n;
    }
}

// ---------------------------------------------------------------------------
// kA2: partial t via row-suffix outer products.
//   Tp[rb][b][j] = sum_{h in [h_lo,h_hi), h<j} x[b,h] * M[h,j]
// Block (c, rb): 192 threads, thread t owns column quad [4t, 4t+4).
// Row h read as CONTIGUOUS suffix M[h, h+1 : 768] (exec-masked lanes skip) --
// the triangle is read exactly once, coalesced. Register accumulator
// (8 samples x 1 float4 = 32 VGPR); no shuffle-reduce needed.
// ---------------------------------------------------------------------------
__global__ __launch_bounds__(192, 4) void kA2(
    const float* __restrict__ x, const int* __restrict__ y,
    const float* __restrict__ M, float* __restrict__ Tp)
{
    const int c    = blockIdx.y;
    const int rb   = blockIdx.x;
    const int t    = threadIdx.x;
    const int h_lo = hb_tab[rb], h_hi = hb_tab[rb + 1];
    const int W    = h_hi - h_lo;             // even, <= 220

    __shared__ int   slist[BATCH];
    __shared__ int   scnt;
    __shared__ float xs[SG][224];             // 7.2 KB

    build_list(y, c, slist, &scnt, t);
    __syncthreads();
    const int cnt = scnt;
    if (cnt == 0) return;

    const float* __restrict__ Mc = M + (size_t)c * HID * HID;
    const int jb = 4 * t;                     // my column quad base

    for (int g0 = 0; g0 < cnt; g0 += SG) {
        const int gs = min(SG, cnt - g0);
        __syncthreads();                      // prev group fully done
        {   // stage x rows [h_lo, h_hi): 24 threads per sample
            const int s = t / 24, l = t - s * 24;
            const int b = slist[g0 + (s < gs ? s : 0)];
            const float4* xr = (const float4*)(x + (size_t)b * HID + h_lo);
            #pragma unroll
            for (int k2 = 0; k2 < 3; ++k2) {
                const int idx = l + 24 * k2;
                if (idx * 4 < W) *(float4*)&xs[s][idx * 4] = xr[idx];
            }
        }
        __syncthreads();

        float4 a[SG];
        #pragma unroll
        for (int s = 0; s < SG; ++s) { a[s].x = 0.f; a[s].y = 0.f; a[s].z = 0.f; a[s].w = 0.f; }

        for (int h = h_lo; h < h_hi; h += 2) {    // W even; 2 rows in flight
            float4 m0, m1;
            m0.x = m0.y = m0.z = m0.w = 0.f;
            m1.x = m1.y = m1.z = m1.w = 0.f;
            if (jb + 3 > h)     m0 = *(const float4*)(Mc + (size_t)h * HID + jb);
            if (jb + 3 > h + 1) m1 = *(const float4*)(Mc + (size_t)(h + 1) * HID + jb);
            // keep element j=jb+e iff j > h (strict upper triangle)
            if (jb + 0 <= h) m0.x = 0.f;
            if (jb + 1 <= h) m0.y = 0.f;
            if (jb + 2 <= h) m0.z = 0.f;
            if (jb + 3 <= h) m0.w = 0.f;
            if (jb + 0 <= h + 1) m1.x = 0.f;
            if (jb + 1 <= h + 1) m1.y = 0.f;
            if (jb + 2 <= h + 1) m1.z = 0.f;
            if (jb + 3 <= h + 1) m1.w = 0.f;
            const int hr = h - h_lo;
            #pragma unroll
            for (int s = 0; s < SG; ++s) {
                const float x0 = xs[s][hr], x1 = xs[s][hr + 1];
                a[s].x = fmaf(x0, m0.x, a[s].x);
                a[s].y = fmaf(x0, m0.y, a[s].y);
                a[s].z = fmaf(x0, m0.z, a[s].z);
                a[s].w = fmaf(x0, m0.w, a[s].w);
                a[s].x = fmaf(x1, m1.x, a[s].x);
                a[s].y = fmaf(x1, m1.y, a[s].y);
                a[s].z = fmaf(x1, m1.z, a[s].z);
                a[s].w = fmaf(x1, m1.w, a[s].w);
            }
        }
        // write partials (zeros below the block's reach are valid partials)
        float* __restrict__ Tpr = Tp + (size_t)rb * BH;
        for (int s = 0; s < gs; ++s)
            *(float4*)(Tpr + (size_t)slist[g0 + s] * HID + jb) = a[s];
    }
}

// ---------------------------------------------------------------------------
// kT: assemble t.  T[b,j] = sum_rb Tp[rb][b][j] + d_j x_j + 1e-3 (X - x_j).
// One block per sample (512 blocks).
// ---------------------------------------------------------------------------
__global__ __launch_bounds__(256) void kT(
    const float* __restrict__ x, const int* __restrict__ y,
    const float* __restrict__ M, const float* __restrict__ Tp,
    float* __restrict__ T)
{
    const int b = blockIdx.x, t = threadIdx.x;
    const int c = y[b];
    __shared__ float wred[4];

    const size_t bh = (size_t)b * HID;
    const float xv0 = x[bh + t], xv1 = x[bh + t + 256], xv2 = x[bh + t + 512];
    float sx = xv0 + xv1 + xv2;
    #pragma unroll
    for (int off = 32; off; off >>= 1) sx += __shfl_xor(sx, off);
    if ((t & 63) == 0) wred[t >> 6] = sx;
    __syncthreads();
    const float X = (wred[0] + wred[1]) + (wred[2] + wred[3]);

    const float* __restrict__ Mc = M + (size_t)c * HID * HID;
    const float xx[3] = {xv0, xv1, xv2};
    #pragma unroll
    for (int qi = 0; qi < 3; ++qi) {
        const int j = t + 256 * qi;
        float u = 0.f;
        #pragma unroll
        for (int rb = 0; rb < 12; ++rb)
            u += Tp[(size_t)rb * BH + bh + j];
        const float dj = fmaxf(Mc[(size_t)j * (HID + 1)], 1e-3f);
        T[bh + j] = u + dj * xx[qi] + 1e-3f * (X - xx[qi]);
    }
}

// ---------------------------------------------------------------------------
// Kernel B (R10-verbatim): out[b, k] for k in 64-row panel K=[64q, 64q+64).
//   out_k = sum_{j>k} M[k,j] t_j + d_k t_k + 1e-3 (Tt - t_k)
// Grid (NPAN, NCLASS); kr = t>>4, cg = t&15.
// ---------------------------------------------------------------------------
__global__ __launch_bounds__(256, 4) void kB(
    const int* __restrict__ y, const float* __restrict__ M,
    const float* __restrict__ T, float* __restrict__ out)
{
    const int c  = blockIdx.y;
    const int q  = blockIdx.x;
    const int t  = threadIdx.x;
    const int k0 = q * 64;

    __shared__ int   slist[BATCH];
    __shared__ int   scnt;
    __shared__ float ts[SG][HID];
    __shared__ float Tt[SG];
    __shared__ float ob[SG][64];
    __shared__ float dk_lds[64];

    build_list(y, c, slist, &scnt, t);
    __syncthreads();
    const int cnt = scnt;
    if (cnt == 0) return;

    const float* __restrict__ Mc = M + (size_t)c * HID * HID;
    const int wv = t >> 6, ln = t & 63;
    const int kr = t >> 4, cg = t & 15;

    if (t < 64) {
        const int kg = k0 + t;
        dk_lds[t] = fmaxf(Mc[(size_t)kg * HID + kg], 1e-3f);
    }

    for (int g0 = 0; g0 < cnt; g0 += SG) {
        const int gs = min(SG, cnt - g0);
        __syncthreads();
        #pragma unroll
        for (int ss = 0; ss < 2; ++ss) {
            const int s = 2 * wv + ss;
            const int b = slist[g0 + (s < gs ? s : 0)];
            const float4* tr = (const float4*)(T + (size_t)b * HID);
            const float4 v0 = tr[ln], v1 = tr[ln + 64], v2 = tr[ln + 128];
            *(float4*)&ts[s][ln * 4]       = v0;
            *(float4*)&ts[s][ln * 4 + 256] = v1;
            *(float4*)&ts[s][ln * 4 + 512] = v2;
            float pT = ((v0.x + v0.y) + (v0.z + v0.w))
                     + ((v1.x + v1.y) + (v1.z + v1.w))
                     + ((v2.x + v2.y) + (v2.z + v2.w));
            #pragma unroll
            for (int off = 32; off; off >>= 1) pT += __shfl_xor(pT, off);
            if (ln == 0) Tt[s] = pT;
        }
        __syncthreads();

        float acc[4][SG];
        #pragma unroll
        for (int m = 0; m < 4; ++m)
            #pragma unroll
            for (int s = 0; s < SG; ++s) acc[m][s] = 0.f;

        for (int jbq = k0; jbq < HID; jbq += 64) {
            const int j0 = jbq + cg * 4;
            float4 mq[4];
            #pragma unroll
            for (int m = 0; m < 4; ++m) {
                const int k = k0 + 16 * m + kr;
                mq[m] = *(const float4*)(Mc + (size_t)k * HID + j0);
                if (jbq == k0) {              // diag-crossing chunk: keep j>k
                    if (j0 + 0 <= k) mq[m].x = 0.f;
                    if (j0 + 1 <= k) mq[m].y = 0.f;
                    if (j0 + 2 <= k) mq[m].z = 0.f;
                    if (j0 + 3 <= k) mq[m].w = 0.f;
                }
            }
            #pragma unroll
            for (int s = 0; s < SG; ++s) {
                const float4 tv = *(const float4*)&ts[s][j0];
                #pragma unroll
                for (int m = 0; m < 4; ++m) {
                    acc[m][s] = fmaf(mq[m].x, tv.x, acc[m][s]);
                    acc[m][s] = fmaf(mq[m].y, tv.y, acc[m][s]);
                    acc[m][s] = fmaf(mq[m].z, tv.z, acc[m][s]);
                    acc[m][s] = fmaf(mq[m].w, tv.w, acc[m][s]);
                }
            }
        }
        #pragma unroll
        for (int m2 = 1; m2 <= 8; m2 <<= 1)
            #pragma unroll
            for (int m = 0; m < 4; ++m)
                #pragma unroll
                for (int s = 0; s < SG; ++s)
                    acc[m][s] += __shfl_xor(acc[m][s], m2);
        if (cg == 0) {
            #pragma unroll
            for (int m = 0; m < 4; ++m)
                #pragma unroll
                for (int s = 0; s < SG; ++s)
                    ob[s][16 * m + kr] = acc[m][s];
        }
        __syncthreads();
        {
            const int j = t & 63;
            const int k = k0 + j;
            #pragma unroll
            for (int ss = 0; ss < 2; ++ss) {
                const int s = (t >> 6) * 2 + ss;
                if (s < gs) {
                    const float tk = ts[s][k];
                    out[(size_t)slist[g0 + s] * HID + k] =
                        ob[s][j] + dk_lds[j] * tk + 1e-3f * (Tt[s] - tk);
                }
            }
        }
    }
}

extern "C" void kernel_launch(void* const* d_in, const int* in_sizes, int n_in,
                              void* d_out, int out_size, void* d_ws, size_t ws_size,
                              hipStream_t stream) {
    const float* x = (const float*)d_in[0];
    const int*   y = (const int*)d_in[1];
    const float* M = (const float*)d_in[2];
    float* out = (float*)d_out;

    float* Tp = (float*)d_ws;                      // 12 * BH floats (18 MiB)
    float* T  = (float*)d_ws + 12 * (size_t)BH;    // 1  * BH (1.5 MiB)

    kA2<<<dim3(12, NCLASS), 192, 0, stream>>>(x, y, M, Tp);
    kT<<<dim3(BATCH), 256, 0, stream>>>(x, y, M, Tp, T);
    kB<<<dim3(NPAN, NCLASS), 256, 0, stream>>>(y, M, T, out);
}

// Round 13
// 141.527 us; speedup vs baseline: 1.1554x; 1.1554x over previous
//
#include <hip/hip_runtime.h>

#define NCLASS 100
#define HID    768
#define BATCH  512
#define SG     8
#define NPAN   12      // 12 panels of 64 columns/rows

// Deterministic per-class sample list (wave 0 of each block).
__device__ __forceinline__ void build_list(const int* __restrict__ y, int c,
                                           int* slist, int* scnt, int t) {
    if (t < 64) {
        int n = 0;
        for (int r = 0; r < BATCH / 64; ++r) {
            const int b = r * 64 + t;
            const bool hit = (y[b] == c);
            const unsigned long long mask = __ballot(hit);
            if (hit) slist[n + __popcll(mask & ((1ull << t) - 1ull))] = b;
            n += __popcll(mask);
        }
        if (t == 0) *scnt = n;
    }
}

// ---------------------------------------------------------------------------
// Kernel A: t[b, j] for j in 64-col panel J=[64g, 64g+64), b in class c.
//   t_j = sum_{h<j} x_h M[h,j] + d_j x_j + 1e-3 (X - x_j), d_j=max(M[j,j],1e-3)
// Grid (NPAN, NCLASS) (R10 champion ordering). Chunks of 64 rows are
// SOFTWARE-PIPELINED: chunk ci+1's 4 loads issue before chunk ci's FMAs, so
// HBM latency hides under compute. Diag chunk (last) masked in registers.
// Thread map: hg = t>>4 (16 rows/chunk-quarter), jq = t&15 (16 col-quads).
// ---------------------------------------------------------------------------
__global__ __launch_bounds__(256, 4) void kA(
    const float* __restrict__ x, const int* __restrict__ y,
    const float* __restrict__ M, float* __restrict__ T)
{
    const int c    = blockIdx.y;
    const int g    = (NPAN - 1) - blockIdx.x;   // big panels dispatch first
    const int t    = threadIdx.x;
    const int col0 = g * 64;
    const int nch  = g + 1;                     // bulk chunks + diag chunk

    __shared__ int   slist[BATCH];
    __shared__ int   scnt;
    __shared__ float xs[SG][HID];         // 24 KB
    __shared__ float Xs[SG];
    __shared__ float red[4][16][4][SG];   // 8 KB
    __shared__ float dj_lds[64];

    build_list(y, c, slist, &scnt, t);
    __syncthreads();
    const int cnt = scnt;
    if (cnt == 0) return;

    const float* __restrict__ Mc   = M + (size_t)c * HID * HID;
    const float* __restrict__ Mpan = Mc + col0 + (t & 15) * 4;
    const int wv = t >> 6, ln = t & 63;
    const int hg = t >> 4, jq = t & 15;

    if (t < 64) {
        const int jg = col0 + t;
        dj_lds[t] = fmaxf(Mc[(size_t)jg * HID + jg], 1e-3f);
    }

#define KA_LOAD(R0, R1, R2, R3, ci)                                          \
    {   const size_t rb_ = (size_t)((ci) * 64 + hg);                         \
        R0 = *(const float4*)(Mpan + (rb_     ) * HID);                      \
        R1 = *(const float4*)(Mpan + (rb_ + 16) * HID);                      \
        R2 = *(const float4*)(Mpan + (rb_ + 32) * HID);                      \
        R3 = *(const float4*)(Mpan + (rb_ + 48) * HID); }

#define KA_MASK1(R, mi)                                                      \
    {   const int hrel_ = hg + 16 * (mi);                                    \
        if (4 * jq + 0 <= hrel_) R.x = 0.f;                                  \
        if (4 * jq + 1 <= hrel_) R.y = 0.f;                                  \
        if (4 * jq + 2 <= hrel_) R.z = 0.f;                                  \
        if (4 * jq + 3 <= hrel_) R.w = 0.f; }

#define KA_FMA1(R, mi, ci)                                                   \
    {   const int h_ = (ci) * 64 + hg + 16 * (mi);                           \
        _Pragma("unroll")                                                    \
        for (int s = 0; s < SG; ++s) {                                       \
            const float xv_ = xs[s][h_];                                     \
            tp[0][s] = fmaf(xv_, R.x, tp[0][s]);                             \
            tp[1][s] = fmaf(xv_, R.y, tp[1][s]);                             \
            tp[2][s] = fmaf(xv_, R.z, tp[2][s]);                             \
            tp[3][s] = fmaf(xv_, R.w, tp[3][s]);                             \
        } }

#define KA_COMP(R0, R1, R2, R3, ci)                                          \
    { KA_FMA1(R0, 0, ci) KA_FMA1(R1, 1, ci) KA_FMA1(R2, 2, ci) KA_FMA1(R3, 3, ci) }

#define KA_MASKD(R0, R1, R2, R3)                                             \
    { KA_MASK1(R0, 0) KA_MASK1(R1, 1) KA_MASK1(R2, 2) KA_MASK1(R3, 3) }

    for (int g0 = 0; g0 < cnt; g0 += SG) {
        const int gs = min(SG, cnt - g0);
        __syncthreads();                      // prev group done; dj_lds visible
        // stage x rows: wave wv stages samples 2wv, 2wv+1; also row-sums X
        #pragma unroll
        for (int ss = 0; ss < 2; ++ss) {
            const int s = 2 * wv + ss;
            const int b = slist[g0 + (s < gs ? s : 0)];
            const float4* xr = (const float4*)(x + (size_t)b * HID);
            const float4 v0 = xr[ln], v1 = xr[ln + 64], v2 = xr[ln + 128];
            *(float4*)&xs[s][ln * 4]       = v0;
            *(float4*)&xs[s][ln * 4 + 256] = v1;
            *(float4*)&xs[s][ln * 4 + 512] = v2;
            float pX = ((v0.x + v0.y) + (v0.z + v0.w))
                     + ((v1.x + v1.y) + (v1.z + v1.w))
                     + ((v2.x + v2.y) + (v2.z + v2.w));
            #pragma unroll
            for (int off = 32; off; off >>= 1) pX += __shfl_xor(pX, off);
            if (ln == 0) Xs[s] = pX;
        }
        __syncthreads();                      // xs, Xs visible

        float tp[4][SG];
        #pragma unroll
        for (int jj = 0; jj < 4; ++jj)
            #pragma unroll
            for (int s = 0; s < SG; ++s) tp[jj][s] = 0.f;

        // ---- software-pipelined chunk loop (ping-pong A/B) ----
        float4 A0, A1, A2, A3, B0, B1, B2, B3;
        KA_LOAD(A0, A1, A2, A3, 0)
        int ci = 0;
        for (; ci + 2 <= nch; ci += 2) {
            KA_LOAD(B0, B1, B2, B3, ci + 1)           // in flight during A FMAs
            KA_COMP(A0, A1, A2, A3, ci)               // ci < nch-1 here: bulk
            if (ci + 2 < nch) KA_LOAD(A0, A1, A2, A3, ci + 2)
            if (ci + 1 == nch - 1) KA_MASKD(B0, B1, B2, B3)
            KA_COMP(B0, B1, B2, B3, ci + 1)
        }
        if (ci < nch) {                               // tail = diag chunk
            KA_MASKD(A0, A1, A2, A3)
            KA_COMP(A0, A1, A2, A3, ci)
        }

        // reduce the 4 row-groups within each wave (lane bits 4,5)
        #pragma unroll
        for (int m = 16; m <= 32; m <<= 1)
            #pragma unroll
            for (int jj = 0; jj < 4; ++jj)
                #pragma unroll
                for (int s = 0; s < SG; ++s)
                    tp[jj][s] += __shfl_xor(tp[jj][s], m);
        if (ln < 16) {
            #pragma unroll
            for (int jj = 0; jj < 4; ++jj)
                #pragma unroll
                for (int s = 0; s < SG; ++s)
                    red[wv][ln][jj][s] = tp[jj][s];
        }
        __syncthreads();                      // red visible
        {   // finalize: thread t handles col j = t&63 for 2 samples
            const int j = t & 63, jq2 = j >> 2, jj2 = j & 3;
            const int jg = col0 + j;
            #pragma unroll
            for (int ss = 0; ss < 2; ++ss) {
                const int s = (t >> 6) * 2 + ss;
                if (s < gs) {
                    const float u = (red[0][jq2][jj2][s] + red[1][jq2][jj2][s])
                                  + (red[2][jq2][jj2][s] + red[3][jq2][jj2][s]);
                    const float xj = xs[s][jg];
                    T[(size_t)slist[g0 + s] * HID + jg] =
                        u + dj_lds[j] * xj + 1e-3f * (Xs[s] - xj);
                }
            }
        }
    }
#undef KA_LOAD
#undef KA_MASK1
#undef KA_FMA1
#undef KA_COMP
#undef KA_MASKD
}

// ---------------------------------------------------------------------------
// Kernel B: out[b, k] for k in 64-row panel K=[64q, 64q+64), b in class c.
//   out_k = sum_{j>k} M[k,j] t_j + d_k t_k + 1e-3 (Tt - t_k)
// Grid (NPAN, NCLASS), q = blockIdx.x (q=0, biggest, first). Chunks of 64
// cols software-pipelined ping-pong; chunk 0 (diag-crossing) masked in regs.
// Thread map: kr = t>>4 (16 rows x 4 m-chunks), cg = t&15 (16 col-quads).
// ---------------------------------------------------------------------------
__global__ __launch_bounds__(256, 4) void kB(
    const int* __restrict__ y, const float* __restrict__ M,
    const float* __restrict__ T, float* __restrict__ out)
{
    const int c   = blockIdx.y;
    const int q   = blockIdx.x;
    const int t   = threadIdx.x;
    const int k0  = q * 64;
    const int nch = NPAN - q;                 // chunks; chunk 0 = diag-crossing

    __shared__ int   slist[BATCH];
    __shared__ int   scnt;
    __shared__ float ts[SG][HID];         // 24 KB
    __shared__ float Tt[SG];
    __shared__ float ob[SG][64];
    __shared__ float dk_lds[64];

    build_list(y, c, slist, &scnt, t);
    __syncthreads();
    const int cnt = scnt;
    if (cnt == 0) return;

    const float* __restrict__ Mc = M + (size_t)c * HID * HID;
    const int wv = t >> 6, ln = t & 63;
    const int kr = t >> 4, cg = t & 15;

    if (t < 64) {
        const int kg = k0 + t;
        dk_lds[t] = fmaxf(Mc[(size_t)kg * HID + kg], 1e-3f);
    }

#define KB_LOAD(R0, R1, R2, R3, ci)                                          \
    {   const size_t jo_ = (size_t)(k0 + (ci) * 64 + cg * 4);                \
        R0 = *(const float4*)(Mc + (size_t)(k0 + kr     ) * HID + jo_);      \
        R1 = *(const float4*)(Mc + (size_t)(k0 + kr + 16) * HID + jo_);      \
        R2 = *(const float4*)(Mc + (size_t)(k0 + kr + 32) * HID + jo_);      \
        R3 = *(const float4*)(Mc + (size_t)(k0 + kr + 48) * HID + jo_); }

#define KB_MASK1(R, mi)                                                      \
    {   const int k_ = k0 + 16 * (mi) + kr, j0_ = k0 + cg * 4;               \
        if (j0_ + 0 <= k_) R.x = 0.f;                                        \
        if (j0_ + 1 <= k_) R.y = 0.f;                                        \
        if (j0_ + 2 <= k_) R.z = 0.f;                                        \
        if (j0_ + 3 <= k_) R.w = 0.f; }

#define KB_COMP(R0, R1, R2, R3, ci)                                          \
    {   const int j0_ = k0 + (ci) * 64 + cg * 4;                             \
        _Pragma("unroll")                                                    \
        for (int s = 0; s < SG; ++s) {                                       \
            const float4 tv_ = *(const float4*)&ts[s][j0_];                  \
            acc[0][s] = fmaf(R0.x, tv_.x, acc[0][s]);                        \
            acc[0][s] = fmaf(R0.y, tv_.y, acc[0][s]);                        \
            acc[0][s] = fmaf(R0.z, tv_.z, acc[0][s]);                        \
            acc[0][s] = fmaf(R0.w, tv_.w, acc[0][s]);                        \
            acc[1][s] = fmaf(R1.x, tv_.x, acc[1][s]);                        \
            acc[1][s] = fmaf(R1.y, tv_.y, acc[1][s]);                        \
            acc[1][s] = fmaf(R1.z, tv_.z, acc[1][s]);                        \
            acc[1][s] = fmaf(R1.w, tv_.w, acc[1][s]);                        \
            acc[2][s] = fmaf(R2.x, tv_.x, acc[2][s]);                        \
            acc[2][s] = fmaf(R2.y, tv_.y, acc[2][s]);                        \
            acc[2][s] = fmaf(R2.z, tv_.z, acc[2][s]);                        \
            acc[2][s] = fmaf(R2.w, tv_.w, acc[2][s]);                        \
            acc[3][s] = fmaf(R3.x, tv_.x, acc[3][s]);                        \
            acc[3][s] = fmaf(R3.y, tv_.y, acc[3][s]);                        \
            acc[3][s] = fmaf(R3.z, tv_.z, acc[3][s]);                        \
            acc[3][s] = fmaf(R3.w, tv_.w, acc[3][s]);                        \
        } }

#define KB_MASKD(R0, R1, R2, R3)                                             \
    { KB_MASK1(R0, 0) KB_MASK1(R1, 1) KB_MASK1(R2, 2) KB_MASK1(R3, 3) }

    for (int g0 = 0; g0 < cnt; g0 += SG) {
        const int gs = min(SG, cnt - g0);
        __syncthreads();                      // prev group done; dk_lds visible
        // stage t rows: wave wv stages samples 2wv, 2wv+1; also row-sums Tt
        #pragma unroll
        for (int ss = 0; ss < 2; ++ss) {
            const int s = 2 * wv + ss;
            const int b = slist[g0 + (s < gs ? s : 0)];
            const float4* tr = (const float4*)(T + (size_t)b * HID);
            const float4 v0 = tr[ln], v1 = tr[ln + 64], v2 = tr[ln + 128];
            *(float4*)&ts[s][ln * 4]       = v0;
            *(float4*)&ts[s][ln * 4 + 256] = v1;
            *(float4*)&ts[s][ln * 4 + 512] = v2;
            float pT = ((v0.x + v0.y) + (v0.z + v0.w))
                     + ((v1.x + v1.y) + (v1.z + v1.w))
                     + ((v2.x + v2.y) + (v2.z + v2.w));
            #pragma unroll
            for (int off = 32; off; off >>= 1) pT += __shfl_xor(pT, off);
            if (ln == 0) Tt[s] = pT;
        }
        __syncthreads();                      // ts, Tt visible

        float acc[4][SG];
        #pragma unroll
        for (int m = 0; m < 4; ++m)
            #pragma unroll
            for (int s = 0; s < SG; ++s) acc[m][s] = 0.f;

        // ---- software-pipelined chunk loop (ping-pong A/B) ----
        float4 A0, A1, A2, A3, B0, B1, B2, B3;
        KB_LOAD(A0, A1, A2, A3, 0)
        int ci = 0;
        for (; ci + 2 <= nch; ci += 2) {
            KB_LOAD(B0, B1, B2, B3, ci + 1)
            if (ci == 0) KB_MASKD(A0, A1, A2, A3)
            KB_COMP(A0, A1, A2, A3, ci)
            if (ci + 2 < nch) KB_LOAD(A0, A1, A2, A3, ci + 2)
            KB_COMP(B0, B1, B2, B3, ci + 1)
        }
        if (ci < nch) {                       // tail chunk (diag iff nch==1)
            if (ci == 0) KB_MASKD(A0, A1, A2, A3)
            KB_COMP(A0, A1, A2, A3, ci)
        }

        // reduce over the 16 col-quads (lane bits 0..3)
        #pragma unroll
        for (int m2 = 1; m2 <= 8; m2 <<= 1)
            #pragma unroll
            for (int m = 0; m < 4; ++m)
                #pragma unroll
                for (int s = 0; s < SG; ++s)
                    acc[m][s] += __shfl_xor(acc[m][s], m2);
        if (cg == 0) {
            #pragma unroll
            for (int m = 0; m < 4; ++m)
                #pragma unroll
                for (int s = 0; s < SG; ++s)
                    ob[s][16 * m + kr] = acc[m][s];
        }
        __syncthreads();                      // ob visible
        {   // store: thread t handles k = k0 + (t&63) for 2 samples
            const int j = t & 63;
            const int k = k0 + j;
            #pragma unroll
            for (int ss = 0; ss < 2; ++ss) {
                const int s = (t >> 6) * 2 + ss;
                if (s < gs) {
                    const float tk = ts[s][k];
                    out[(size_t)slist[g0 + s] * HID + k] =
                        ob[s][j] + dk_lds[j] * tk + 1e-3f * (Tt[s] - tk);
                }
            }
        }
    }
#undef KB_LOAD
#undef KB_MASK1
#undef KB_COMP
#undef KB_MASKD
}

extern "C" void kernel_launch(void* const* d_in, const int* in_sizes, int n_in,
                              void* d_out, int out_size, void* d_ws, size_t ws_size,
                              hipStream_t stream) {
    const float* x = (const float*)d_in[0];
    const int*   y = (const int*)d_in[1];
    const float* M = (const float*)d_in[2];
    float* out = (float*)d_out;
    float* T   = (float*)d_ws;   // 512 * 768 * 4 B = 1.5 MiB scratch

    kA<<<dim3(NPAN, NCLASS), 256, 0, stream>>>(x, y, M, T);
    kB<<<dim3(NPAN, NCLASS), 256, 0, stream>>>(y, M, T, out);
}

// Round 14
// 74.777 us; speedup vs baseline: 2.1868x; 1.8926x over previous
//
#include <hip/hip_runtime.h>

#define NCLASS 100
#define HID    768
#define BATCH  512
#define SG     8
#define NPAN   12      // 12 panels of 64 columns/rows
#define NZ     2       // sample-group parallelism (tail killer)

// Deterministic per-class sample list (wave 0 of each block).
__device__ __forceinline__ void build_list(const int* __restrict__ y, int c,
                                           int* slist, int* scnt, int t) {
    if (t < 64) {
        int n = 0;
        for (int r = 0; r < BATCH / 64; ++r) {
            const int b = r * 64 + t;
            const bool hit = (y[b] == c);
            const unsigned long long mask = __ballot(hit);
            if (hit) slist[n + __popcll(mask & ((1ull << t) - 1ull))] = b;
            n += __popcll(mask);
        }
        if (t == 0) *scnt = n;
    }
}

// ---------------------------------------------------------------------------
// Kernel A: t[b, j] for j in 64-col panel J=[64g, 64g+64), b in class c,
// sample-groups z, z+2, ... (z = blockIdx.z kills the 2-pass straggler tail).
//   t_j = sum_{h<j} x_h M[h,j] + d_j x_j + 1e-3 (X - x_j), d_j=max(M[j,j],1e-3)
// Grid (NPAN, NCLASS, NZ). Thread map: hg = t>>4, jq = t&15.
// ---------------------------------------------------------------------------
__global__ __launch_bounds__(256, 4) void kA(
    const float* __restrict__ x, const int* __restrict__ y,
    const float* __restrict__ M, float* __restrict__ T)
{
    const int c    = blockIdx.y;
    const int g    = (NPAN - 1) - blockIdx.x;   // big panels dispatch first
    const int z    = blockIdx.z;
    const int t    = threadIdx.x;
    const int col0 = g * 64;

    __shared__ int   slist[BATCH];
    __shared__ int   scnt;
    __shared__ float xs[SG][HID];         // 24 KB
    __shared__ float Xs[SG];
    __shared__ float red[4][16][4][SG];   // 8 KB
    __shared__ float dj_lds[64];

    build_list(y, c, slist, &scnt, t);
    __syncthreads();
    const int cnt = scnt;
    if (cnt <= z * SG) return;

    const float* __restrict__ Mc = M + (size_t)c * HID * HID;
    const int wv = t >> 6, ln = t & 63;
    const int hg = t >> 4, jq = t & 15;

    if (t < 64) {
        const int jg = col0 + t;
        dj_lds[t] = fmaxf(Mc[(size_t)jg * HID + jg], 1e-3f);
    }

    for (int g0 = z * SG; g0 < cnt; g0 += NZ * SG) {
        const int gs = min(SG, cnt - g0);
        __syncthreads();                      // prev group done; dj_lds visible
        // stage x rows: wave wv stages samples 2wv, 2wv+1; also row-sums X
        #pragma unroll
        for (int ss = 0; ss < 2; ++ss) {
            const int s = 2 * wv + ss;
            const int b = slist[g0 + (s < gs ? s : 0)];
            const float4* xr = (const float4*)(x + (size_t)b * HID);
            const float4 v0 = xr[ln], v1 = xr[ln + 64], v2 = xr[ln + 128];
            *(float4*)&xs[s][ln * 4]       = v0;
            *(float4*)&xs[s][ln * 4 + 256] = v1;
            *(float4*)&xs[s][ln * 4 + 512] = v2;
            float pX = ((v0.x + v0.y) + (v0.z + v0.w))
                     + ((v1.x + v1.y) + (v1.z + v1.w))
                     + ((v2.x + v2.y) + (v2.z + v2.w));
            #pragma unroll
            for (int off = 32; off; off >>= 1) pX += __shfl_xor(pX, off);
            if (ln == 0) Xs[s] = pX;
        }
        __syncthreads();                      // xs, Xs visible

        float tp[4][SG];
        #pragma unroll
        for (int jj = 0; jj < 4; ++jj)
            #pragma unroll
            for (int s = 0; s < SG; ++s) tp[jj][s] = 0.f;

        for (int hb = 0; hb < col0; hb += 64) {   // bulk rows h < col0
            float4 ma[4];
            #pragma unroll
            for (int m = 0; m < 4; ++m)
                ma[m] = *(const float4*)(Mc + (size_t)(hb + hg + 16 * m) * HID + col0 + jq * 4);
            #pragma unroll
            for (int m = 0; m < 4; ++m) {
                const int h = hb + hg + 16 * m;
                #pragma unroll
                for (int s = 0; s < SG; ++s) {
                    const float xv = xs[s][h];
                    tp[0][s] = fmaf(xv, ma[m].x, tp[0][s]);
                    tp[1][s] = fmaf(xv, ma[m].y, tp[1][s]);
                    tp[2][s] = fmaf(xv, ma[m].z, tp[2][s]);
                    tp[3][s] = fmaf(xv, ma[m].w, tp[3][s]);
                }
            }
        }
        {   // peeled diagonal 64-row square: strict h<j masks
            float4 ma[4];
            #pragma unroll
            for (int m = 0; m < 4; ++m) {
                const int hrel = hg + 16 * m;
                ma[m] = *(const float4*)(Mc + (size_t)(col0 + hrel) * HID + col0 + jq * 4);
                if (4 * jq + 0 <= hrel) ma[m].x = 0.f;
                if (4 * jq + 1 <= hrel) ma[m].y = 0.f;
                if (4 * jq + 2 <= hrel) ma[m].z = 0.f;
                if (4 * jq + 3 <= hrel) ma[m].w = 0.f;
            }
            #pragma unroll
            for (int m = 0; m < 4; ++m) {
                const int h = col0 + hg + 16 * m;
                #pragma unroll
                for (int s = 0; s < SG; ++s) {
                    const float xv = xs[s][h];
                    tp[0][s] = fmaf(xv, ma[m].x, tp[0][s]);
                    tp[1][s] = fmaf(xv, ma[m].y, tp[1][s]);
                    tp[2][s] = fmaf(xv, ma[m].z, tp[2][s]);
                    tp[3][s] = fmaf(xv, ma[m].w, tp[3][s]);
                }
            }
        }
        // reduce the 4 row-groups within each wave (lane bits 4,5)
        #pragma unroll
        for (int m = 16; m <= 32; m <<= 1)
            #pragma unroll
            for (int jj = 0; jj < 4; ++jj)
                #pragma unroll
                for (int s = 0; s < SG; ++s)
                    tp[jj][s] += __shfl_xor(tp[jj][s], m);
        if (ln < 16) {
            #pragma unroll
            for (int jj = 0; jj < 4; ++jj)
                #pragma unroll
                for (int s = 0; s < SG; ++s)
                    red[wv][ln][jj][s] = tp[jj][s];
        }
        __syncthreads();                      // red visible
        {   // finalize: thread t handles col j = t&63 for 2 samples
            const int j = t & 63, jq2 = j >> 2, jj2 = j & 3;
            const int jg = col0 + j;
            #pragma unroll
            for (int ss = 0; ss < 2; ++ss) {
                const int s = (t >> 6) * 2 + ss;
                if (s < gs) {
                    const float u = (red[0][jq2][jj2][s] + red[1][jq2][jj2][s])
                                  + (red[2][jq2][jj2][s] + red[3][jq2][jj2][s]);
                    const float xj = xs[s][jg];
                    T[(size_t)slist[g0 + s] * HID + jg] =
                        u + dj_lds[j] * xj + 1e-3f * (Xs[s] - xj);
                }
            }
        }
    }
}

// ---------------------------------------------------------------------------
// Kernel B: out[b, k] for k in 64-row panel K=[64q, 64q+64), b in class c,
// sample-groups z, z+2, ...
//   out_k = sum_{j>k} M[k,j] t_j + d_k t_k + 1e-3 (Tt - t_k)
// Grid (NPAN, NCLASS, NZ), q = blockIdx.x (q=0, biggest, first).
// Thread map: kr = t>>4 (16 rows x 4 m-chunks), cg = t&15 (16 col-quads).
// ---------------------------------------------------------------------------
__global__ __launch_bounds__(256, 4) void kB(
    const int* __restrict__ y, const float* __restrict__ M,
    const float* __restrict__ T, float* __restrict__ out)
{
    const int c  = blockIdx.y;
    const int q  = blockIdx.x;
    const int z  = blockIdx.z;
    const int t  = threadIdx.x;
    const int k0 = q * 64;

    __shared__ int   slist[BATCH];
    __shared__ int   scnt;
    __shared__ float ts[SG][HID];         // 24 KB
    __shared__ float Tt[SG];
    __shared__ float ob[SG][64];          // 2 KB
    __shared__ float dk_lds[64];

    build_list(y, c, slist, &scnt, t);
    __syncthreads();
    const int cnt = scnt;
    if (cnt <= z * SG) return;

    const float* __restrict__ Mc = M + (size_t)c * HID * HID;
    const int wv = t >> 6, ln = t & 63;
    const int kr = t >> 4, cg = t & 15;

    if (t < 64) {
        const int kg = k0 + t;
        dk_lds[t] = fmaxf(Mc[(size_t)kg * HID + kg], 1e-3f);
    }

    for (int g0 = z * SG; g0 < cnt; g0 += NZ * SG) {
        const int gs = min(SG, cnt - g0);
        __syncthreads();                      // prev group done (ob reads done)
        // stage t rows: wave wv stages samples 2wv, 2wv+1; also row-sums Tt
        #pragma unroll
        for (int ss = 0; ss < 2; ++ss) {
            const int s = 2 * wv + ss;
            const int b = slist[g0 + (s < gs ? s : 0)];
            const float4* tr = (const float4*)(T + (size_t)b * HID);
            const float4 v0 = tr[ln], v1 = tr[ln + 64], v2 = tr[ln + 128];
            *(float4*)&ts[s][ln * 4]       = v0;
            *(float4*)&ts[s][ln * 4 + 256] = v1;
            *(float4*)&ts[s][ln * 4 + 512] = v2;
            float pT = ((v0.x + v0.y) + (v0.z + v0.w))
                     + ((v1.x + v1.y) + (v1.z + v1.w))
                     + ((v2.x + v2.y) + (v2.z + v2.w));
            #pragma unroll
            for (int off = 32; off; off >>= 1) pT += __shfl_xor(pT, off);
            if (ln == 0) Tt[s] = pT;
        }
        __syncthreads();                      // ts, Tt visible

        float acc[4][SG];
        #pragma unroll
        for (int m = 0; m < 4; ++m)
            #pragma unroll
            for (int s = 0; s < SG; ++s) acc[m][s] = 0.f;

        for (int jb = k0; jb < HID; jb += 64) {
            const int j0 = jb + cg * 4;
            float4 mq[4];
            #pragma unroll
            for (int m = 0; m < 4; ++m) {
                const int k = k0 + 16 * m + kr;
                mq[m] = *(const float4*)(Mc + (size_t)k * HID + j0);
                if (jb == k0) {               // diag-crossing chunk: keep j>k
                    if (j0 + 0 <= k) mq[m].x = 0.f;
                    if (j0 + 1 <= k) mq[m].y = 0.f;
                    if (j0 + 2 <= k) mq[m].z = 0.f;
                    if (j0 + 3 <= k) mq[m].w = 0.f;
                }
            }
            #pragma unroll
            for (int s = 0; s < SG; ++s) {
                const float4 tv = *(const float4*)&ts[s][j0];
                #pragma unroll
                for (int m = 0; m < 4; ++m) {
                    acc[m][s] = fmaf(mq[m].x, tv.x, acc[m][s]);
                    acc[m][s] = fmaf(mq[m].y, tv.y, acc[m][s]);
                    acc[m][s] = fmaf(mq[m].z, tv.z, acc[m][s]);
                    acc[m][s] = fmaf(mq[m].w, tv.w, acc[m][s]);
                }
            }
        }
        // reduce over the 16 col-quads (lane bits 0..3)
        #pragma unroll
        for (int m2 = 1; m2 <= 8; m2 <<= 1)
            #pragma unroll
            for (int m = 0; m < 4; ++m)
                #pragma unroll
                for (int s = 0; s < SG; ++s)
                    acc[m][s] += __shfl_xor(acc[m][s], m2);
        if (cg == 0) {
            #pragma unroll
            for (int m = 0; m < 4; ++m)
                #pragma unroll
                for (int s = 0; s < SG; ++s)
                    ob[s][16 * m + kr] = acc[m][s];
        }
        __syncthreads();                      // ob visible
        // store: thread t handles k = k0 + (t&63) for 2 samples
        {
            const int j = t & 63;
            const int k = k0 + j;
            #pragma unroll
            for (int ss = 0; ss < 2; ++ss) {
                const int s = (t >> 6) * 2 + ss;
                if (s < gs) {
                    const float tk = ts[s][k];
                    out[(size_t)slist[g0 + s] * HID + k] =
                        ob[s][j] + dk_lds[j] * tk + 1e-3f * (Tt[s] - tk);
                }
            }
        }
    }
}

extern "C" void kernel_launch(void* const* d_in, const int* in_sizes, int n_in,
                              void* d_out, int out_size, void* d_ws, size_t ws_size,
                              hipStream_t stream) {
    const float* x = (const float*)d_in[0];
    const int*   y = (const int*)d_in[1];
    const float* M = (const float*)d_in[2];
    float* out = (float*)d_out;
    float* T   = (float*)d_ws;   // 512 * 768 * 4 B = 1.5 MiB scratch

    kA<<<dim3(NPAN, NCLASS, NZ), 256, 0, stream>>>(x, y, M, T);
    kB<<<dim3(NPAN, NCLASS, NZ), 256, 0, stream>>>(y, M, T, out);
}